// Round 1
// baseline (1164.260 us; speedup 1.0000x reference)
//
#include <hip/hip_runtime.h>
#include <hip/hip_cooperative_groups.h>

namespace cg = cooperative_groups;

#define N_ROWS 1024
#define M_COLS 16384
#define DIM 512
#define NM (N_ROWS * M_COLS)

constexpr float GAMMA_ = 0.1f;
constexpr float INV_GAMMA = 10.0f;
constexpr float EPS_ = 0.005f;
constexpr float TINY_ = 1e-30f;
constexpr float RVAL = 1.0f / 1024.0f;
constexpr float CVAL = 1.0f / 16384.0f;

__device__ __forceinline__ float waveRedSum(float v) {
#pragma unroll
    for (int o = 32; o > 0; o >>= 1) v += __shfl_down(v, o);
    return v;
}
__device__ __forceinline__ float waveRedMin(float v) {
#pragma unroll
    for (int o = 32; o > 0; o >>= 1) v = fminf(v, __shfl_down(v, o));
    return v;
}

// ---- sq norms: one block (128 thr) per row ----
__global__ void row_sqnorm(const float* __restrict__ X, float* __restrict__ out) {
    int row = blockIdx.x;
    const float* xr = X + (size_t)row * DIM;
    int tid = threadIdx.x;
    float acc = 0.f;
    for (int k = tid; k < DIM; k += 128) { float v = xr[k]; acc = fmaf(v, v, acc); }
    acc = waveRedSum(acc);
    __shared__ float red[2];
    if ((tid & 63) == 0) red[tid >> 6] = acc;
    __syncthreads();
    if (tid == 0) out[row] = red[0] + red[1];
}

// ---- M = sx + sy - 2*X@Y^T  (f32, 128x128 tile, 8x8/thread) ----
__global__ __launch_bounds__(256) void gemm_dist(const float* __restrict__ X, const float* __restrict__ Y,
                                                 const float* __restrict__ sx, const float* __restrict__ sy,
                                                 float* __restrict__ Mout) {
    alignas(16) __shared__ float As[16][132];
    alignas(16) __shared__ float Bs[16][132];
    const int tid = threadIdx.x;
    const int tx = tid & 15, ty = tid >> 4;
    const int row0 = blockIdx.y * 128, col0 = blockIdx.x * 128;
    float acc[8][8] = {};
    for (int k0 = 0; k0 < DIM; k0 += 16) {
#pragma unroll
        for (int p = 0; p < 2; ++p) {
            int idx = tid + (p << 8);
            int r = idx >> 2;
            int kq = (idx & 3) << 2;
            float4 va = *(const float4*)(X + (size_t)(row0 + r) * DIM + k0 + kq);
            As[kq + 0][r] = va.x; As[kq + 1][r] = va.y; As[kq + 2][r] = va.z; As[kq + 3][r] = va.w;
            float4 vb = *(const float4*)(Y + (size_t)(col0 + r) * DIM + k0 + kq);
            Bs[kq + 0][r] = vb.x; Bs[kq + 1][r] = vb.y; Bs[kq + 2][r] = vb.z; Bs[kq + 3][r] = vb.w;
        }
        __syncthreads();
#pragma unroll
        for (int kk = 0; kk < 16; ++kk) {
            float a[8], b[8];
            *(float4*)&a[0] = *(const float4*)&As[kk][ty * 8];
            *(float4*)&a[4] = *(const float4*)&As[kk][ty * 8 + 4];
            *(float4*)&b[0] = *(const float4*)&Bs[kk][tx * 8];
            *(float4*)&b[4] = *(const float4*)&Bs[kk][tx * 8 + 4];
#pragma unroll
            for (int i = 0; i < 8; ++i)
#pragma unroll
                for (int j = 0; j < 8; ++j)
                    acc[i][j] = fmaf(a[i], b[j], acc[i][j]);
        }
        __syncthreads();
    }
#pragma unroll
    for (int i = 0; i < 8; ++i) {
        int gr = row0 + ty * 8 + i;
        float sxi = sx[gr];
        float* orow = Mout + (size_t)gr * M_COLS + col0 + tx * 8;
#pragma unroll
        for (int j = 0; j < 8; ++j) {
            orow[j] = sxi + sy[col0 + tx * 8 + j] - 2.0f * acc[i][j];
        }
    }
}

// ---- row min of M ----
__global__ void row_min(const float* __restrict__ Mb, float* __restrict__ Mmin) {
    int row = blockIdx.x;
    const float* mr = Mb + (size_t)row * M_COLS;
    int tid = threadIdx.x;
    float mn = INFINITY;
    for (int j = tid; j < M_COLS; j += 256) mn = fminf(mn, mr[j]);
    mn = waveRedMin(mn);
    __shared__ float red[4];
    if ((tid & 63) == 0) red[tid >> 6] = mn;
    __syncthreads();
    if (tid == 0) Mmin[row] = fminf(fminf(red[0], red[1]), fminf(red[2], red[3]));
}

// ---- K = exp(-gamma*(M - Mmin)), in place ----
__global__ void exp_kernel(float* __restrict__ Mb, const float* __restrict__ Mmin) {
    int stride = gridDim.x * blockDim.x;
    for (int idx = blockIdx.x * blockDim.x + threadIdx.x; idx < NM; idx += stride) {
        int i = idx >> 14;
        float m = Mb[idx];
        Mb[idx] = __expf(-GAMMA_ * (m - Mmin[i]));
    }
}

// ---- init small state (every call: harness poisons ws once, never re-poisons) ----
__global__ void init_state(float* __restrict__ u, float* __restrict__ v0,
                           float* __restrict__ errslots, float* __restrict__ lossacc,
                           int* __restrict__ rec) {
    int idx = blockIdx.x * blockDim.x + threadIdx.x;
    int stride = gridDim.x * blockDim.x;
    for (int k = idx; k < M_COLS; k += stride) v0[k] = 1.0f;
    for (int k = idx; k < N_ROWS; k += stride) { u[k] = 1.0f; errslots[k] = 0.0f; }
    if (idx == 0) { lossacc[0] = 0.0f; rec[0] = 0; rec[1] = 0; }
}

// ---- persistent Sinkhorn loop (cooperative, 256 blocks x 256 thr) ----
// P = diag(u) K diag(v).  Per iter: s=Kv, u=u*r/max(u*s,TINY); t=K^T u,
// beta=v*t, err=sum|beta-c|; if err>EPS: v=v*c/max(beta,TINY) (ping-pong buffer).
__global__ __launch_bounds__(256) void sinkhorn_loop(const float* __restrict__ Kc, float* __restrict__ u,
                                                     float* __restrict__ va, float* __restrict__ vb1,
                                                     float* __restrict__ errslots, int* __restrict__ rec) {
    cg::grid_group grid = cg::this_grid();
    __shared__ float sred[16];
    __shared__ float tred[4][64];
    const int tid = threadIdx.x;
    const int lane = tid & 63, wid = tid >> 6;
    float* vb[2] = {va, vb1};
    int cur = 0;
    int it = 0;
    for (it = 0; it < 1000; ++it) {
        const float* __restrict__ vcur = vb[cur];
        // pass 1: s_i = sum_j K_ij v_j for the 4 rows this block owns
#pragma unroll 1
        for (int rr = 0; rr < 4; ++rr) {
            int row = (blockIdx.x << 2) + rr;
            const float* Krow = Kc + ((size_t)row << 14);
            float acc = 0.f;
            for (int j = tid; j < M_COLS; j += 256) acc = fmaf(Krow[j], vcur[j], acc);
            acc = waveRedSum(acc);
            if (lane == 0) sred[rr * 4 + wid] = acc;
        }
        __syncthreads();
        if (tid < 4) {
            int row = (blockIdx.x << 2) + tid;
            float s = sred[tid * 4] + sred[tid * 4 + 1] + sred[tid * 4 + 2] + sred[tid * 4 + 3];
            float up = u[row];
            u[row] = up * RVAL / fmaxf(up * s, TINY_);
        }
        grid.sync();
        // pass 2: t_j = sum_i K_ij u_i for the 64 cols this block owns
        {
            int j = (blockIdx.x << 6) + lane;
            int i0 = wid << 8;
            const float* Kp = Kc + (size_t)i0 * M_COLS + j;
            float acc = 0.f;
            for (int ii = 0; ii < 256; ++ii) acc = fmaf(Kp[(size_t)ii * M_COLS], u[i0 + ii], acc);
            tred[wid][lane] = acc;
        }
        __syncthreads();
        if (wid == 0) {
            int j = (blockIdx.x << 6) + lane;
            float t = tred[0][lane] + tred[1][lane] + tred[2][lane] + tred[3][lane];
            float vc = vb[cur][j];
            float beta = vc * t;
            float e = fabsf(beta - CVAL);
            vb[cur ^ 1][j] = vc * CVAL / fmaxf(beta, TINY_);  // speculative update
            e = waveRedSum(e);
            if (lane == 0) atomicAdd(&errslots[it], e);
        }
        grid.sync();
        float err = errslots[it];
        if (err <= EPS_) break;   // keep old v (matches reference Pn=P1)
        cur ^= 1;                 // accept updated v
    }
    if (blockIdx.x == 0 && tid == 0) { rec[0] = cur; rec[1] = (it < 1000 ? it + 1 : 1000); }
}

// ---- P = u K v in place; loss += P * (Mmin - ln K / gamma) ----
__global__ void finalize(float* __restrict__ KP, const float* __restrict__ u,
                         const float* __restrict__ va, const float* __restrict__ vb1,
                         const float* __restrict__ Mmin, const int* __restrict__ rec,
                         float* __restrict__ lossacc) {
    const float* v = rec[0] ? vb1 : va;
    int stride = gridDim.x * blockDim.x;
    float lsum = 0.f;
    for (int idx = blockIdx.x * blockDim.x + threadIdx.x; idx < NM; idx += stride) {
        float k = KP[idx];
        int i = idx >> 14, j = idx & (M_COLS - 1);
        float p = 0.f;
        if (k > 0.f) {
            p = u[i] * k * v[j];
            float mv = Mmin[i] - __logf(k) * INV_GAMMA;
            lsum = fmaf(p, mv, lsum);
        }
        KP[idx] = p;
    }
    lsum = waveRedSum(lsum);
    __shared__ float red[4];
    if ((threadIdx.x & 63) == 0) red[threadIdx.x >> 6] = lsum;
    __syncthreads();
    if (threadIdx.x == 0) atomicAdd(lossacc, red[0] + red[1] + red[2] + red[3]);
}

__global__ void write_loss(float* __restrict__ out, const float* __restrict__ lossacc) {
    out[0] = lossacc[0];
}

extern "C" void kernel_launch(void* const* d_in, const int* in_sizes, int n_in,
                              void* d_out, int out_size, void* d_ws, size_t ws_size,
                              hipStream_t stream) {
    const float* x = (const float*)d_in[0];
    const float* y = (const float*)d_in[1];
    float* out = (float*)d_out;
    float* P = out + 1;              // 16.7M floats: used as K during the loop, P at the end
    float* ws = (float*)d_ws;
    float* sx       = ws;            // 1024
    float* sy       = ws + 1024;     // 16384
    float* Mmin     = ws + 17408;    // 1024
    float* u        = ws + 18432;    // 1024
    float* v0       = ws + 19456;    // 16384
    float* v1       = ws + 35840;    // 16384
    float* errslots = ws + 52224;    // 1024 (>= MAXITERS)
    float* lossacc  = ws + 53248;    // 1
    int*   rec      = (int*)(ws + 53250); // 2 ints, 8B-aligned

    row_sqnorm<<<N_ROWS, 128, 0, stream>>>(x, sx);
    row_sqnorm<<<M_COLS, 128, 0, stream>>>(y, sy);
    init_state<<<64, 256, 0, stream>>>(u, v0, errslots, lossacc, rec);
    gemm_dist<<<dim3(128, 8), 256, 0, stream>>>(x, y, sx, sy, P);
    row_min<<<N_ROWS, 256, 0, stream>>>(P, Mmin);
    exp_kernel<<<4096, 256, 0, stream>>>(P, Mmin);
    {
        const float* Kc = P;
        void* args[] = {(void*)&Kc, (void*)&u, (void*)&v0, (void*)&v1, (void*)&errslots, (void*)&rec};
        hipLaunchCooperativeKernel((const void*)sinkhorn_loop, dim3(256), dim3(256), args, 0, stream);
    }
    finalize<<<4096, 256, 0, stream>>>(P, u, v0, v1, Mmin, rec, lossacc);
    write_loss<<<1, 1, 0, stream>>>(out, lossacc);
}

// Round 2
// 803.442 us; speedup vs baseline: 1.4491x; 1.4491x over previous
//
#include <hip/hip_runtime.h>
#include <hip/hip_cooperative_groups.h>

namespace cg = cooperative_groups;

#define N_ROWS 1024
#define M_COLS 16384
#define DIM 512

constexpr float GAMMA_ = 0.1f;
constexpr float INV_GAMMA = 10.0f;
constexpr float EPS_ = 0.005f;
constexpr float TINY_ = 1e-30f;
constexpr float RVAL = 1.0f / 1024.0f;
constexpr float CVAL = 1.0f / 16384.0f;

__device__ __forceinline__ float waveRedSum(float v) {
#pragma unroll
    for (int o = 32; o > 0; o >>= 1) v += __shfl_down(v, o);
    return v;
}
__device__ __forceinline__ float waveRedMin(float v) {
#pragma unroll
    for (int o = 32; o > 0; o >>= 1) v = fminf(v, __shfl_down(v, o));
    return v;
}

// ---- sq norms: one block (128 thr) per row ----
__global__ void row_sqnorm(const float* __restrict__ X, float* __restrict__ out) {
    int row = blockIdx.x;
    const float* xr = X + (size_t)row * DIM;
    int tid = threadIdx.x;
    float acc = 0.f;
    for (int k = tid; k < DIM; k += 128) { float v = xr[k]; acc = fmaf(v, v, acc); }
    acc = waveRedSum(acc);
    __shared__ float red[2];
    if ((tid & 63) == 0) red[tid >> 6] = acc;
    __syncthreads();
    if (tid == 0) out[row] = red[0] + red[1];
}

// ---- M = sx + sy - 2*X@Y^T  (f32, 128x128 tile, 8x8/thread) ----
__global__ __launch_bounds__(256) void gemm_dist(const float* __restrict__ X, const float* __restrict__ Y,
                                                 const float* __restrict__ sx, const float* __restrict__ sy,
                                                 float* __restrict__ Mout) {
    alignas(16) __shared__ float As[16][132];
    alignas(16) __shared__ float Bs[16][132];
    const int tid = threadIdx.x;
    const int tx = tid & 15, ty = tid >> 4;
    const int row0 = blockIdx.y * 128, col0 = blockIdx.x * 128;
    float acc[8][8] = {};
    for (int k0 = 0; k0 < DIM; k0 += 16) {
#pragma unroll
        for (int p = 0; p < 2; ++p) {
            int idx = tid + (p << 8);
            int r = idx >> 2;
            int kq = (idx & 3) << 2;
            float4 va = *(const float4*)(X + (size_t)(row0 + r) * DIM + k0 + kq);
            As[kq + 0][r] = va.x; As[kq + 1][r] = va.y; As[kq + 2][r] = va.z; As[kq + 3][r] = va.w;
            float4 vb = *(const float4*)(Y + (size_t)(col0 + r) * DIM + k0 + kq);
            Bs[kq + 0][r] = vb.x; Bs[kq + 1][r] = vb.y; Bs[kq + 2][r] = vb.z; Bs[kq + 3][r] = vb.w;
        }
        __syncthreads();
#pragma unroll
        for (int kk = 0; kk < 16; ++kk) {
            float a[8], b[8];
            *(float4*)&a[0] = *(const float4*)&As[kk][ty * 8];
            *(float4*)&a[4] = *(const float4*)&As[kk][ty * 8 + 4];
            *(float4*)&b[0] = *(const float4*)&Bs[kk][tx * 8];
            *(float4*)&b[4] = *(const float4*)&Bs[kk][tx * 8 + 4];
#pragma unroll
            for (int i = 0; i < 8; ++i)
#pragma unroll
                for (int j = 0; j < 8; ++j)
                    acc[i][j] = fmaf(a[i], b[j], acc[i][j]);
        }
        __syncthreads();
    }
#pragma unroll
    for (int i = 0; i < 8; ++i) {
        int gr = row0 + ty * 8 + i;
        float sxi = sx[gr];
        float* orow = Mout + (size_t)gr * M_COLS + col0 + tx * 8;
#pragma unroll
        for (int j = 0; j < 8; ++j) {
            orow[j] = sxi + sy[col0 + tx * 8 + j] - 2.0f * acc[i][j];
        }
    }
}

// ---- row min of M ----
__global__ void row_min(const float* __restrict__ Mb, float* __restrict__ Mmin) {
    int row = blockIdx.x;
    const float* mr = Mb + (size_t)row * M_COLS;
    int tid = threadIdx.x;
    float mn = INFINITY;
    for (int j = tid; j < M_COLS; j += 256) mn = fminf(mn, mr[j]);
    mn = waveRedMin(mn);
    __shared__ float red[4];
    if ((tid & 63) == 0) red[tid >> 6] = mn;
    __syncthreads();
    if (tid == 0) Mmin[row] = fminf(fminf(red[0], red[1]), fminf(red[2], red[3]));
}

// ---- register-resident Sinkhorn: K lives in VGPRs of 256 blocks x 1024 thr ----
// Block b owns cols [64b, 64b+64); thread (rg=tid>>2, ch=tid&3) owns rows
// 4rg..4rg+3 x cols {64b + ch + 4c, c=0..15}: K[4][16] = 64 VGPRs.
// v is block-local (LDS ping-pong). u is global (ws), owner block b updates
// rows 4b..4b+3. s-partials + err-partials live in the (consumed) M region
// of d_out. 2 grid syncs per iteration.
__global__ __launch_bounds__(1024, 4) void sinkhorn_reg(const float* __restrict__ Mmin,
                                                        float* __restrict__ u,
                                                        float* __restrict__ Pbuf,
                                                        float* __restrict__ out0) {
    cg::grid_group grid = cg::this_grid();
    const int tid = threadIdx.x;
    const int b = blockIdx.x;
    const int rg = tid >> 2;
    const int ch = tid & 3;
    const int r0 = rg << 2;
    const int c0 = b << 6;
    float* spart = Pbuf;                 // [1024][256] floats (over dead M rows 0..15)
    float* errpart = Pbuf + 262144;      // [256]

    __shared__ float v_lds[2][64];
    __shared__ float t_acc[16][68];
    __shared__ float red[16];

    if (tid < 64) { v_lds[0][tid] = 1.0f; v_lds[1][tid] = 1.0f; }
    if (tid < 4) u[(b << 2) + tid] = 1.0f;
    if (b == 0 && tid == 0) out0[0] = 0.0f;

    // ---- load phase: K = exp(-gamma*(M - Mmin)) into registers ----
    float K[64];
#pragma unroll
    for (int k = 0; k < 4; ++k) {
        const float* mrow = Pbuf + (size_t)(r0 + k) * M_COLS + c0 + ch;
        float mm = Mmin[r0 + k];
#pragma unroll
        for (int c = 0; c < 16; ++c) {
            K[k * 16 + c] = __expf(-GAMMA_ * (mrow[4 * c] - mm));
        }
    }
    grid.sync();   // M fully consumed; scratch regions now safe to write

    int cur = 0;
    int vsel = 0;
    for (int it = 0; it <= 1000; ++it) {
        if (it < 1000) {
            // ---- pass 1: s-partials (this block's 64-col contribution) ----
            float vv[16];
#pragma unroll
            for (int c = 0; c < 16; ++c) vv[c] = v_lds[cur][ch + 4 * c];
            float rs[4];
#pragma unroll
            for (int k = 0; k < 4; ++k) {
                float p = 0.f;
#pragma unroll
                for (int c = 0; c < 16; ++c) p = fmaf(K[k * 16 + c], vv[c], p);
                rs[k] = p;
            }
#pragma unroll
            for (int k = 0; k < 4; ++k) {
                rs[k] += __shfl_xor(rs[k], 1);
                rs[k] += __shfl_xor(rs[k], 2);
            }
            if (ch == 0) {
#pragma unroll
                for (int k = 0; k < 4; ++k) spart[(size_t)(r0 + k) * 256 + b] = rs[k];
            }
        }
        grid.sync();   // A: s-partials + prev err-partials visible
        // ---- err decision (uniform across all blocks, deterministic sum) ----
        float err;
        if (it > 0) {
            float e = (tid < 256) ? errpart[tid] : 0.f;
            e = waveRedSum(e);
            if ((tid & 63) == 0) red[tid >> 6] = e;
            __syncthreads();
            err = red[0] + red[1] + red[2] + red[3];
            __syncthreads();
        } else {
            err = 1e30f;
        }
        if (err <= EPS_) { vsel = cur ^ 1; break; }       // converged: keep pre-update v
        if (it == 1000) { vsel = cur; break; }            // exhausted: keep updated v
        // ---- u update: block b reduces rows 4b..4b+3 ----
        if (tid < 256) {
            int w = tid >> 6, l = tid & 63;
            int row = (b << 2) + w;
            const float* sp = spart + (size_t)row * 256;
            float acc = sp[l] + sp[l + 64] + sp[l + 128] + sp[l + 192];
            acc = waveRedSum(acc);
            if (l == 0) {
                float uo = u[row];
                u[row] = uo * RVAL / fmaxf(uo * acc, TINY_);
            }
        }
        grid.sync();   // B: all u finalized
        // ---- pass 2: t = K^T u (block-local cols), v update, err-partial ----
        float4 u4v = *(const float4*)(u + r0);
        float uu[4] = {u4v.x, u4v.y, u4v.z, u4v.w};
        float t16[16];
#pragma unroll
        for (int c = 0; c < 16; ++c) {
            float t = 0.f;
#pragma unroll
            for (int k = 0; k < 4; ++k) t = fmaf(K[k * 16 + c], uu[k], t);
            t16[c] = t;
        }
#pragma unroll
        for (int c = 0; c < 16; ++c) {
            t16[c] += __shfl_xor(t16[c], 4);
            t16[c] += __shfl_xor(t16[c], 8);
            t16[c] += __shfl_xor(t16[c], 16);
            t16[c] += __shfl_xor(t16[c], 32);
        }
        {
            int w = tid >> 6, l = tid & 63;
            if (l < 4) {
#pragma unroll
                for (int c = 0; c < 16; ++c) t_acc[w][l + 4 * c] = t16[c];
            }
        }
        __syncthreads();
        if (tid < 64) {
            float t = 0.f;
#pragma unroll
            for (int w2 = 0; w2 < 16; ++w2) t += t_acc[w2][tid];
            float vc = v_lds[cur][tid];
            float beta = vc * t;
            float e = fabsf(beta - CVAL);
            v_lds[cur ^ 1][tid] = vc * CVAL / fmaxf(beta, TINY_);
            e = waveRedSum(e);
            if (tid == 0) errpart[b] = e;
        }
        __syncthreads();
        cur ^= 1;
    }

    grid.sync();   // all blocks done with scratch reads before P overwrites it

    // ---- epilogue: P = u K v (from regs), loss = sum P*(Mmin - ln(K)/gamma) ----
    float vv[16];
#pragma unroll
    for (int c = 0; c < 16; ++c) vv[c] = v_lds[vsel][ch + 4 * c];
    float4 u4v = *(const float4*)(u + r0);
    float uu[4] = {u4v.x, u4v.y, u4v.z, u4v.w};
    float4 mm4 = *(const float4*)(Mmin + r0);
    float mm[4] = {mm4.x, mm4.y, mm4.z, mm4.w};
    float lsum = 0.f;
#pragma unroll
    for (int k = 0; k < 4; ++k) {
        float* prow = Pbuf + (size_t)(r0 + k) * M_COLS + c0 + ch;
#pragma unroll
        for (int c = 0; c < 16; ++c) {
            float kv = K[k * 16 + c];
            float p = 0.f;
            if (kv > 0.f) {
                p = uu[k] * kv * vv[c];
                float m = mm[k] - __logf(kv) * INV_GAMMA;
                lsum = fmaf(p, m, lsum);
            }
            prow[4 * c] = p;
        }
    }
    lsum = waveRedSum(lsum);
    if ((tid & 63) == 0) red[tid >> 6] = lsum;
    __syncthreads();
    if (tid == 0) {
        float s = 0.f;
#pragma unroll
        for (int i = 0; i < 16; ++i) s += red[i];
        atomicAdd(out0, s);
    }
}

extern "C" void kernel_launch(void* const* d_in, const int* in_sizes, int n_in,
                              void* d_out, int out_size, void* d_ws, size_t ws_size,
                              hipStream_t stream) {
    const float* x = (const float*)d_in[0];
    const float* y = (const float*)d_in[1];
    float* out = (float*)d_out;
    float* P = out + 1;              // 16.7M floats: M -> (scratch) -> P
    float* ws = (float*)d_ws;
    float* sx   = ws;                // 1024
    float* sy   = ws + 1024;         // 16384
    float* Mmin = ws + 17408;        // 1024
    float* u    = ws + 18432;        // 1024

    row_sqnorm<<<N_ROWS, 128, 0, stream>>>(x, sx);
    row_sqnorm<<<M_COLS, 128, 0, stream>>>(y, sy);
    gemm_dist<<<dim3(128, 8), 256, 0, stream>>>(x, y, sx, sy, P);
    row_min<<<N_ROWS, 256, 0, stream>>>(P, Mmin);
    {
        const float* Mminc = Mmin;
        void* args[] = {(void*)&Mminc, (void*)&u, (void*)&P, (void*)&out};
        hipLaunchCooperativeKernel((const void*)sinkhorn_reg, dim3(256), dim3(1024), args, 0, stream);
    }
}